// Round 1
// baseline (579.231 us; speedup 1.0000x reference)
//
#include <hip/hip_runtime.h>

#define T_LEN 1024
#define B_SZ 4
#define EMB 1024
#define NH 16
#define HD 64
#define QKV_LD 3072

typedef _Float16 f16;
typedef __attribute__((ext_vector_type(8))) _Float16 f16x8;
typedef __attribute__((ext_vector_type(4))) _Float16 f16x4;
typedef __attribute__((ext_vector_type(4))) float f32x4;

// async global->LDS, 16B per lane. LDS dest must be wave-uniform base + lane*16.
__device__ __forceinline__ void gload16(const f16* g, f16* l) {
    __builtin_amdgcn_global_load_lds(
        (const __attribute__((address_space(1))) void*)g,
        (__attribute__((address_space(3))) void*)l, 16, 0, 0);
}

// ---------------------------------------------------------------------------
// fused fp32->fp16 conversion for query / W_in / W_out (one launch)
// ---------------------------------------------------------------------------
#define N4_Q  (4096 * 1024 / 4)
#define N4_WI (3072 * 1024 / 4)
#define N4_WO (1024 * 1024 / 4)
__global__ __launch_bounds__(256) void cvt_all(
    const float* __restrict__ q, const float* __restrict__ wi,
    const float* __restrict__ wo, f16* __restrict__ q16,
    f16* __restrict__ wi16, f16* __restrict__ wo16)
{
    int i = blockIdx.x * 256 + threadIdx.x;
    const float* src; f16* dst; int off;
    if (i < N4_Q)             { src = q;  dst = q16;  off = i; }
    else if (i < N4_Q + N4_WI){ src = wi; dst = wi16; off = i - N4_Q; }
    else                      { src = wo; dst = wo16; off = i - N4_Q - N4_WI; }
    float4 v = ((const float4*)src)[off];
    f16x4 h = { (f16)v.x, (f16)v.y, (f16)v.z, (f16)v.w };
    ((f16x4*)dst)[off] = h;
}

// ---------------------------------------------------------------------------
// Transposed f16 MFMA GEMM: Out[x][e] = sum_k Wt[e][k]*Xa[x][k] + bias[e].
// 128x128 tile, BK=32, m97-style global_load_lds staging, unpadded [128][32].
// (unchanged — control variable; counters next round attribute its cost)
// ---------------------------------------------------------------------------
template<bool OUT_HALF>
__global__ __launch_bounds__(256) void gemm_ct(
    const f16* __restrict__ Wt, const f16* __restrict__ Xa,
    const float* __restrict__ bias, void* __restrict__ Out,
    int K, int ldo)
{
    __shared__ f16 As[128 * 32];
    __shared__ f16 Bs[128 * 32];
    const int tid = threadIdx.x;
    const int wv = tid >> 6, lane = tid & 63;
    const int lq = lane & 15, quad = lane >> 4;
    const int m0 = blockIdx.x * 128, n0 = blockIdx.y * 128;
    const int wm = (wv >> 1) * 64, wn = (wv & 1) * 64;

    const int s1 = tid, s2 = 256 + tid;
    const f16* a1 = Wt + (size_t)(m0 + (s1 >> 2)) * K + (s1 & 3) * 8;
    const f16* a2 = Wt + (size_t)(m0 + (s2 >> 2)) * K + (s2 & 3) * 8;
    const f16* b1 = Xa + (size_t)(n0 + (s1 >> 2)) * K + (s1 & 3) * 8;
    const f16* b2 = Xa + (size_t)(n0 + (s2 >> 2)) * K + (s2 & 3) * 8;
    f16* lA1 = As + s1 * 8; f16* lA2 = As + s2 * 8;
    f16* lB1 = Bs + s1 * 8; f16* lB2 = Bs + s2 * 8;

    f32x4 acc[4][4];
#pragma unroll
    for (int i = 0; i < 4; ++i)
#pragma unroll
        for (int j = 0; j < 4; ++j) acc[i][j] = (f32x4){0.f, 0.f, 0.f, 0.f};

    for (int k0 = 0; k0 < K; k0 += 32) {
        __syncthreads();
        gload16(a1 + k0, lA1);
        gload16(a2 + k0, lA2);
        gload16(b1 + k0, lB1);
        gload16(b2 + k0, lB2);
        __syncthreads();
        f16x8 af[4], bf[4];
#pragma unroll
        for (int t = 0; t < 4; ++t) {
            af[t] = *(const f16x8*)&As[(wm + t * 16 + lq) * 32 + quad * 8];
            bf[t] = *(const f16x8*)&Bs[(wn + t * 16 + lq) * 32 + quad * 8];
        }
#pragma unroll
        for (int mt = 0; mt < 4; ++mt)
#pragma unroll
            for (int nt = 0; nt < 4; ++nt)
                acc[mt][nt] = __builtin_amdgcn_mfma_f32_16x16x32_f16(
                    af[mt], bf[nt], acc[mt][nt], 0, 0, 0);
    }

#pragma unroll
    for (int mt = 0; mt < 4; ++mt) {
        const int e0 = m0 + wm + mt * 16 + quad * 4;
        const float4 bb = *(const float4*)(bias + e0);
#pragma unroll
        for (int nt = 0; nt < 4; ++nt) {
            const int xr = n0 + wn + nt * 16 + lq;
            if (OUT_HALF) {
                f16x4 h = { (f16)(acc[mt][nt][0] + bb.x), (f16)(acc[mt][nt][1] + bb.y),
                            (f16)(acc[mt][nt][2] + bb.z), (f16)(acc[mt][nt][3] + bb.w) };
                *(f16x4*)((f16*)Out + (size_t)xr * ldo + e0) = h;
            } else {
                float4 o = { acc[mt][nt][0] + bb.x, acc[mt][nt][1] + bb.y,
                             acc[mt][nt][2] + bb.z, acc[mt][nt][3] + bb.w };
                *(float4*)((float*)Out + (size_t)xr * ldo + e0) = o;
            }
        }
    }
}

// ---------------------------------------------------------------------------
// V transpose: qkv natural v-section -> Vth[bh][d][t].  (unchanged)
// ---------------------------------------------------------------------------
__global__ __launch_bounds__(256) void vtrans(
    const f16* __restrict__ qkv, f16* __restrict__ Vth)
{
    __shared__ f16 Ls[256 * 66];
    const int bh = blockIdx.x;
    const int t0 = blockIdx.y * 256;
    const int b = bh >> 4, hh = bh & 15;
    const int tid = threadIdx.x;

#pragma unroll
    for (int p = 0; p < 8; ++p) {
        const int g = p * 2048 + tid * 8;
        const int ti = g >> 6, dj = g & 63;
        f16x8 v = *(const f16x8*)(qkv + (size_t)((t0 + ti) * 4 + b) * QKV_LD + 2048 + hh * 64 + dj);
        *(f16x8*)&Ls[ti * 66 + dj] = v;
    }
    __syncthreads();
#pragma unroll
    for (int p = 0; p < 8; ++p) {
        const int g = p * 2048 + tid * 8;
        const int d = g >> 8, tt = g & 255;
        f16x8 o;
#pragma unroll
        for (int j = 0; j < 8; ++j) o[j] = Ls[(tt + j) * 66 + d];
        *(f16x8*)(Vth + (size_t)bh * 65536 + (size_t)d * 1024 + t0 + tt) = o;
    }
}

// ---------------------------------------------------------------------------
// Fused flash attention v5. Changes vs v4 (all occupancy / latency-hiding):
//  - bias prefetch granularity 128->64 keys, one-iteration lookahead
//    (bcur/bnxt: 32 VGPR instead of bb/bbn's 64; same ~1k-cycle lead)
//  - V fragment loads issued AFTER QK^T MFMAs -> L2 latency hides under
//    the softmax VALU chain instead of stacking at subtile start
//  - __launch_bounds__(256,3): target <=168 VGPR, 3 waves/SIMD (was ~240/2)
//  - defer-max (T13): skip O-rescale + alpha shfl-transpose when
//    __all(rm <= m_i + 8); P bounded by e^8, fits f16
//  - s_setprio(1) around MFMA clusters (T5; independent-wave regime)
// ---------------------------------------------------------------------------
__global__ __launch_bounds__(256, 3) void attn_v5(
    const f16* __restrict__ qkv, const f16* __restrict__ Vth,
    const int* __restrict__ kpm, const float* __restrict__ attn_mask,
    const float* __restrict__ attn_bias, f16* __restrict__ ctx)
{
    const int LDP = 72;
    __shared__ f16 Ps[4 * 16 * LDP];

    const int tid = threadIdx.x;
    const int wv = tid >> 6, lane = tid & 63;
    const int lq = lane & 15, quad = lane >> 4;
    const int q0 = blockIdx.x * 64;
    const int bh = blockIdx.y;
    const int b = bh >> 4, hh = bh & 15;
    f16* Pw = Ps + wv * 16 * LDP;

    const int t = q0 + wv * 16 + lq;
    const float* mrow = attn_mask + (size_t)t * T_LEN;
    const float* brow = attn_bias + ((size_t)bh * T_LEN + t) * T_LEN;
    const int* kpr = kpm + b * T_LEN;
    const f16* Vb = Vth + (size_t)bh * 65536;

    f16x8 bq[2];
    {
        const f16* qrow = qkv + (size_t)(t * 4 + b) * QKV_LD + hh * 64;
        bq[0] = *(const f16x8*)(qrow + quad * 8);
        bq[1] = *(const f16x8*)(qrow + 32 + quad * 8);
    }

    float m_i = -1e30f, l_i = 0.0f;
    f32x4 O[4];
#pragma unroll
    for (int dt = 0; dt < 4; ++dt) O[dt] = (f32x4){0.f, 0.f, 0.f, 0.f};

    // bias for the first 64-key subtile (nontemporal: zero reuse)
    f32x4 bcur[4];
#pragma unroll
    for (int st = 0; st < 4; ++st)
        bcur[st] = __builtin_nontemporal_load((const f32x4*)(brow + st * 16 + quad * 4));

#pragma unroll 1
    for (int sh = 0; sh < T_LEN; sh += 64) {
        // (0) prefetch bias for the NEXT subtile (one-iteration lead ~ HBM lat)
        f32x4 bnxt[4];
        if (sh + 64 < T_LEN) {
#pragma unroll
            for (int st = 0; st < 4; ++st)
                bnxt[st] = __builtin_nontemporal_load(
                    (const f32x4*)(brow + sh + 64 + st * 16 + quad * 4));
        }

        // (1) K fragments (consumed first, by QK^T)
        f16x8 ak[2][4];
#pragma unroll
        for (int ks = 0; ks < 2; ++ks)
#pragma unroll
            for (int st = 0; st < 4; ++st)
                ak[ks][st] = *(const f16x8*)(qkv
                    + (size_t)((sh + st * 16 + lq) * 4 + b) * QKV_LD
                    + EMB + hh * 64 + ks * 32 + quad * 8);

        // (2) mask + kpm (L2/L3-hot; consumed in the softmax prologue)
        f32x4 m4[4]; int4 kp4[4];
#pragma unroll
        for (int st = 0; st < 4; ++st) {
            const int sb = sh + st * 16 + quad * 4;
            m4[st] = *(const f32x4*)(mrow + sb);
            kp4[st] = *(const int4*)(kpr + sb);
        }

        // ---- S^T = K Q^T ----
        f32x4 sacc[4];
#pragma unroll
        for (int st = 0; st < 4; ++st) sacc[st] = (f32x4){0.f, 0.f, 0.f, 0.f};
        __builtin_amdgcn_s_setprio(1);
#pragma unroll
        for (int ks = 0; ks < 2; ++ks)
#pragma unroll
            for (int st = 0; st < 4; ++st)
                sacc[st] = __builtin_amdgcn_mfma_f32_16x16x32_f16(
                    ak[ks][st], bq[ks], sacc[st], 0, 0, 0);
        __builtin_amdgcn_s_setprio(0);

        // (3) V fragments: issue now, consume after softmax -> latency hidden
        f16x8 av[2][4];
#pragma unroll
        for (int ks = 0; ks < 2; ++ks)
#pragma unroll
            for (int dt = 0; dt < 4; ++dt)
                av[ks][dt] = *(const f16x8*)(Vb + (size_t)(dt * 16 + lq) * 1024
                                             + sh + ks * 32 + quad * 8);

        // ---- scale + mask + bias + kpm ----
        float sv[4][4];
        float rm = -1e30f;
#pragma unroll
        for (int st = 0; st < 4; ++st) {
            const int kv[4] = {kp4[st].x, kp4[st].y, kp4[st].z, kp4[st].w};
#pragma unroll
            for (int r = 0; r < 4; ++r) {
                const float x = sacc[st][r] * 0.125f + m4[st][r] + bcur[st][r];
                sv[st][r] = kv[r] ? -1e30f : x;
                rm = fmaxf(rm, sv[st][r]);
            }
        }
        rm = fmaxf(rm, __shfl_xor(rm, 16));
        rm = fmaxf(rm, __shfl_xor(rm, 32));

        // defer-max: wave-uniform skip of the O-rescale when max barely grew
        const bool skip = __all(rm <= m_i + 8.0f);
        float alpha;
        if (skip) {
            alpha = 1.0f;
        } else {
            const float mn = fmaxf(m_i, rm);
            alpha = __expf(m_i - mn);
            m_i = mn;
        }

        __builtin_amdgcn_wave_barrier();   // prev P reads precede overwrite
        float rs = 0.0f;
#pragma unroll
        for (int st = 0; st < 4; ++st) {
            f16x4 pv;
#pragma unroll
            for (int r = 0; r < 4; ++r) {
                const float p = __expf(sv[st][r] - m_i);
                rs += p;
                pv[r] = (f16)p;
            }
            *(f16x4*)&Pw[lq * LDP + st * 16 + quad * 4] = pv;
        }
        rs += __shfl_xor(rs, 16);
        rs += __shfl_xor(rs, 32);
        l_i = l_i * alpha + rs;

        if (!skip) {
            float aB[4];
#pragma unroll
            for (int r = 0; r < 4; ++r) aB[r] = __shfl(alpha, quad * 4 + r, 16);
#pragma unroll
            for (int dt = 0; dt < 4; ++dt)
#pragma unroll
                for (int r = 0; r < 4; ++r) O[dt][r] *= aB[r];
        }

        __builtin_amdgcn_wave_barrier();   // P writes precede P reads

        // ---- O += P V ----
        __builtin_amdgcn_s_setprio(1);
#pragma unroll
        for (int ks = 0; ks < 2; ++ks) {
            const f16x8 ap = *(const f16x8*)&Pw[lq * LDP + ks * 32 + quad * 8];
#pragma unroll
            for (int dt = 0; dt < 4; ++dt)
                O[dt] = __builtin_amdgcn_mfma_f32_16x16x32_f16(
                    ap, av[ks][dt], O[dt], 0, 0, 0);
        }
        __builtin_amdgcn_s_setprio(0);

        // rotate bias buffer
#pragma unroll
        for (int st = 0; st < 4; ++st) bcur[st] = bnxt[st];
    }

    // epilogue
    float lB[4];
#pragma unroll
    for (int r = 0; r < 4; ++r) lB[r] = __shfl(l_i, quad * 4 + r, 16);
#pragma unroll
    for (int r = 0; r < 4; ++r) {
        const float inv = 1.0f / lB[r];
        const int tt = q0 + wv * 16 + quad * 4 + r;
#pragma unroll
        for (int dt = 0; dt < 4; ++dt)
            ctx[((size_t)tt * B_SZ + b) * EMB + hh * HD + dt * 16 + lq] = (f16)(O[dt][r] * inv);
    }
}

// ---------------------------------------------------------------------------
extern "C" void kernel_launch(void* const* d_in, const int* in_sizes, int n_in,
                              void* d_out, int out_size, void* d_ws, size_t ws_size,
                              hipStream_t stream)
{
    const float* query     = (const float*)d_in[0];
    const int*   kpm       = (const int*)  d_in[1];
    const float* attn_mask = (const float*)d_in[2];
    const float* attn_bias = (const float*)d_in[3];
    const float* W_in      = (const float*)d_in[4];
    const float* b_in      = (const float*)d_in[5];
    const float* W_out     = (const float*)d_in[6];
    const float* b_out     = (const float*)d_in[7];
    float* out = (float*)d_out;

    f16* q16    = (f16*)d_ws;                                   // 4096x1024
    f16* win16  = q16    + (size_t)4096 * 1024;                 // 3072x1024
    f16* wout16 = win16  + (size_t)3072 * 1024;                 // 1024x1024
    f16* qkv16  = wout16 + (size_t)1024 * 1024;                 // 4096x3072
    f16* Vth    = qkv16  + (size_t)4096 * 3072;                 // 64 x 64 x 1024
    f16* ctx16  = Vth    + (size_t)64 * 65536;                  // 4096x1024

    cvt_all<<<(N4_Q + N4_WI + N4_WO) / 256, 256, 0, stream>>>(
        query, W_in, W_out, q16, win16, wout16);

    dim3 g1(3072 / 128, 4096 / 128);
    gemm_ct<true><<<g1, 256, 0, stream>>>(win16, q16, b_in, qkv16, 1024, QKV_LD);

    dim3 gv(64, 4);
    vtrans<<<gv, 256, 0, stream>>>(qkv16, Vth);

    dim3 g2(T_LEN / 64, B_SZ * NH);
    attn_v5<<<g2, 256, 0, stream>>>(qkv16, Vth, kpm, attn_mask, attn_bias, ctx16);

    dim3 g3(1024 / 128, 4096 / 128);
    gemm_ct<false><<<g3, 256, 0, stream>>>(wout16, ctx16, b_out, out, 1024, 1024);
}